// Round 5
// baseline (165.633 us; speedup 1.0000x reference)
//
#include <hip/hip_runtime.h>
#include <stdint.h>

#define U 128
#define V 128
#define IN_STRIDE 512
#define OUT_STRIDE 512
#define W_STRIDE (8 * U * V) /* 131072 floats per expert */
#define NB 32768
#define NE 4

// Workspace layout (bytes)
#define WS_WSHUF 0           // 524288 ushorts (1 MB) shuffled bf16 weights
#define WS_CNT   1048576     // 4 uint per-expert cursors/counts (16 B)
#define WS_SORT  1048640     // 4 * 32768 ints (512 KB): region e at e*NB

typedef __bf16 bf16x8 __attribute__((ext_vector_type(8)));
typedef float f32x4 __attribute__((ext_vector_type(4)));
typedef unsigned int u32x4 __attribute__((ext_vector_type(4)));

static __device__ __forceinline__ unsigned short f2bf(float f) {
    unsigned int u = __builtin_bit_cast(unsigned int, f);
    u += 0x7FFFu + ((u >> 16) & 1u);   // round-to-nearest-even
    return (unsigned short)(u >> 16);
}

// ---------------------------------------------------------------------------
// prep R9: weights fp32 -> bf16 in 16x16x32 MFMA B-fragment layout.
//   shorts offset = ((((e*8+s)*8+nt)*4+ks)*64 + lane)*8 + j
//   element = W[e][s][k = ks*32+(lane>>4)*8+j][n = nt*16+(lane&15)], segs 4..7 x0.5
// Also zeroes the 4 expert cursors.
// ---------------------------------------------------------------------------
__global__ void prep_kernel(const float* __restrict__ w, unsigned short* __restrict__ wshuf,
                            unsigned int* __restrict__ cnt) {
    if (blockIdx.x == 0 && threadIdx.x < NE) cnt[threadIdx.x] = 0u;
    int t = blockIdx.x * 256 + threadIdx.x;   // 0..65535
    int lane = t & 63;
    int ks = (t >> 6) & 3;
    int nt = (t >> 8) & 7;
    int s  = (t >> 11) & 7;
    int e  = (t >> 14) & 3;
    int kbase = ks * 32 + ((lane >> 4) << 3);
    int n = nt * 16 + (lane & 15);
    const float* src = w + (size_t)e * W_STRIDE + (size_t)s * (U * V) + n;
    float sc = (s >= 4) ? 0.5f : 1.0f;
    __attribute__((aligned(16))) unsigned short o[8];
#pragma unroll
    for (int j = 0; j < 8; j++) o[j] = f2bf(src[(size_t)(kbase + j) * V] * sc);
    *(u32x4*)(wshuf + (size_t)t * 8) = *(const u32x4*)o;
}

// ---------------------------------------------------------------------------
// scatter: bucket rows by expert (order within expert irrelevant).
// ---------------------------------------------------------------------------
__global__ void scatter_kernel(const int* __restrict__ wid, unsigned int* __restrict__ cnt,
                               int* __restrict__ sorted) {
    __shared__ unsigned int lcnt[NE];
    __shared__ unsigned int lbase[NE];
    int t = threadIdx.x;
    if (t < NE) lcnt[t] = 0u;
    __syncthreads();
    int i = blockIdx.x * 256 + t;
    int e = wid[i];
    unsigned int lpos = atomicAdd(&lcnt[e], 1u);
    __syncthreads();
    if (t < NE) lbase[t] = atomicAdd(&cnt[t], lcnt[t]);
    __syncthreads();
    sorted[e * NB + (int)(lbase[e] + lpos)] = i;
}

// ---------------------------------------------------------------------------
// gemm R9: break the 2-block lockstep with TLP. R8 (2 blocks/CU, 2-phase
// stage->barrier->compute) measured 37% HBM duty, occupancy 26% -- half the
// waves parked at the barrier. R9: 16-row tiles (32 KB LDS), 16x16x32 MFMA,
// 512 thr, __launch_bounds__(512,8) -> 4 blocks/CU x 8 waves = 32 waves/CU,
// 4 independently-phased blocks per CU (2048 blocks, 2 rounds). While one
// block drains its barrier, three others compute/store.
// LDS [16 rows][512 floats] linear (32 KB), staged via global_load_lds
// (4 x 1KB fire-and-forget per wave). Source-side XOR swizzle (rule #21):
// LDS chunk c of row r holds global chunk c ^ (r&7); fragment read XORs back.
// Wave w: out cols w*64..+63 (kout=w>>1, nhalf=w&1); K=256 from x col-blocks
// {kout (seg kout), (kout+3)&3 (seg +4, x0.5 pre-folded)}.
// Fast single-expert path; masked 4-expert path for <=3 boundary tiles.
// ---------------------------------------------------------------------------
__global__ __launch_bounds__(512, 8) void gemm_kernel(
        const float* __restrict__ x, const unsigned short* __restrict__ wshuf,
        const unsigned int* __restrict__ cnt, const int* __restrict__ sorted,
        float* __restrict__ out) {
    const int rowbase = blockIdx.x * 16;
    __shared__ float ldsf[16][512];   // 32 KB
    __shared__ int rowid[16];

    const unsigned int p1 = cnt[0];
    const unsigned int p2 = p1 + cnt[1];
    const unsigned int p3 = p2 + cnt[2];

    const int t = threadIdx.x;
    const int w = t >> 6, lane = t & 63;
    const int l5 = lane >> 5, m0 = lane & 31;
    const int kout = w >> 1, nhalf = w & 1;
    const int m16 = lane & 15;         // A-row / D-col for 16x16
    const int kg = lane >> 4;          // k-group 0..3

    // ---- row ids for this wave's 2 staged rows (rows 2w, 2w+1) ----
    int rid[2];
#pragma unroll
    for (int i = 0; i < 2; i++) {
        unsigned int ls = (unsigned int)(rowbase + 2 * w + i);
        int e = (ls >= p1) + (ls >= p2) + (ls >= p3);
        unsigned int pe = (e == 0) ? 0u : (e == 1) ? p1 : (e == 2) ? p2 : p3;
        rid[i] = sorted[e * NB + (int)(ls - pe)];
    }
    if (t < 16) {
        unsigned int ls = (unsigned int)(rowbase + t);
        int e = (ls >= p1) + (ls >= p2) + (ls >= p3);
        unsigned int pe = (e == 0) ? 0u : (e == 1) ? p1 : (e == 2) ? p2 : p3;
        rowid[t] = sorted[e * NB + (int)(ls - pe)];
    }

    // ---- stage: 2 rows x 2 half-row DMAs, fire-and-forget ----
#pragma unroll
    for (int i = 0; i < 2; i++) {
        int r = 2 * w + i;
        int rs = r & 7;
        const float* xb = x + (size_t)rid[i] * IN_STRIDE + l5 * 128 + ((m0 ^ rs) << 2);
#pragma unroll
        for (int h = 0; h < 2; h++) {
            __builtin_amdgcn_global_load_lds(
                (const __attribute__((address_space(1))) unsigned int*)(xb + h * 256),
                (__attribute__((address_space(3))) unsigned int*)&ldsf[r][h * 256],
                16, 0, 0);
        }
    }

    // expert span / per-lane expert (A-row m16)
    const unsigned int lh = (unsigned int)rowbase, lt = (unsigned int)(rowbase + 15);
    const int ehead = (lh >= p1) + (lh >= p2) + (lh >= p3);
    const int etail = (lt >= p1) + (lt >= p2) + (lt >= p3);
    const unsigned int l0 = (unsigned int)(rowbase + m16);
    const int e0 = (l0 >= p1) + (l0 >= p2) + (l0 >= p3);

    const int xbc1 = (kout + 3) & 3;
    const int xbs[2] = {kout, xbc1};
    const int sgs[2] = {kout, xbc1 + 4};
    const int rsw = m16 & 7;

    f32x4 acc[4] = {};   // acc[ni]: D cols w*64 + ni*16 + (lane&15)

    if (ehead == etail) {
        // ---- fast path: whole 16-row tile is one expert ----
        // B base for (e, sg, nhalf): nt stride 2048 shorts, ks stride 512
        const unsigned short* wb0 =
            wshuf + ((size_t)((ehead * 8 + sgs[0]) * 8 + nhalf * 4)) * 2048 + (size_t)lane * 8;
        const unsigned short* wb1 =
            wshuf + ((size_t)((ehead * 8 + sgs[1]) * 8 + nhalf * 4)) * 2048 + (size_t)lane * 8;
        // preload c=0, s=0 B-frags (L2 latency hides under x-stage drain)
        u32x4 bp[4];
#pragma unroll
        for (int ni = 0; ni < 4; ni++)
            bp[ni] = *(const u32x4*)(wb0 + (size_t)ni * 2048);

        __syncthreads();   // drains vmcnt(0): x-stage AND B-preload

#pragma unroll
        for (int c = 0; c < 2; c++) {
            const float* ar = &ldsf[m16][0];
            const int cb3 = xbs[c] * 32;
            const unsigned short* wb = (c == 0) ? wb0 : wb1;
#pragma unroll
            for (int s = 0; s < 4; s++) {
                int gj0 = cb3 + s * 8 + kg * 2;
                float4 va = *(const float4*)(ar + ((gj0 ^ rsw) << 2));
                float4 vb = *(const float4*)(ar + (((gj0 + 1) ^ rsw) << 2));
                bf16x8 a;
                a[0] = (__bf16)va.x; a[1] = (__bf16)va.y;
                a[2] = (__bf16)va.z; a[3] = (__bf16)va.w;
                a[4] = (__bf16)vb.x; a[5] = (__bf16)vb.y;
                a[6] = (__bf16)vb.z; a[7] = (__bf16)vb.w;
#pragma unroll
                for (int ni = 0; ni < 4; ni++) {
                    bf16x8 b;
                    if (c == 0 && s == 0) b = __builtin_bit_cast(bf16x8, bp[ni]);
                    else b = __builtin_bit_cast(bf16x8,
                             *(const u32x4*)(wb + (size_t)ni * 2048 + (size_t)s * 512));
                    acc[ni] = __builtin_amdgcn_mfma_f32_16x16x32_bf16(a, b, acc[ni], 0, 0, 0);
                }
            }
        }
    } else {
        // ---- boundary tile (<=3 of 2048): masked 4-expert path ----
        unsigned int msk[4];
#pragma unroll
        for (int e = 0; e < 4; e++) msk[e] = (e0 == e) ? 0xFFFFFFFFu : 0u;
        __syncthreads();
#pragma unroll
        for (int c = 0; c < 2; c++) {
            const float* ar = &ldsf[m16][0];
            const int cb3 = xbs[c] * 32;
#pragma unroll
            for (int s = 0; s < 4; s++) {
                int gj0 = cb3 + s * 8 + kg * 2;
                float4 va = *(const float4*)(ar + ((gj0 ^ rsw) << 2));
                float4 vb = *(const float4*)(ar + (((gj0 + 1) ^ rsw) << 2));
                __attribute__((aligned(16))) unsigned short au[8];
                au[0] = f2bf(va.x); au[1] = f2bf(va.y);
                au[2] = f2bf(va.z); au[3] = f2bf(va.w);
                au[4] = f2bf(vb.x); au[5] = f2bf(vb.y);
                au[6] = f2bf(vb.z); au[7] = f2bf(vb.w);
                u32x4 araw = *(const u32x4*)au;
#pragma unroll
                for (int e = 0; e < 4; e++) {
                    u32x4 mm = {msk[e], msk[e], msk[e], msk[e]};
                    bf16x8 am = __builtin_bit_cast(bf16x8, araw & mm);
                    const unsigned short* wbe =
                        wshuf + ((size_t)((e * 8 + sgs[c]) * 8 + nhalf * 4)) * 2048 + (size_t)lane * 8;
#pragma unroll
                    for (int ni = 0; ni < 4; ni++) {
                        bf16x8 b = __builtin_bit_cast(bf16x8,
                            *(const u32x4*)(wbe + (size_t)ni * 2048 + (size_t)s * 512));
                        acc[ni] = __builtin_amdgcn_mfma_f32_16x16x32_bf16(am, b, acc[ni], 0, 0, 0);
                    }
                }
            }
        }
    }

    // ---- epilogue: 16x16 C/D layout col=lane&15, row=(lane>>4)*4+reg ----
    // per store instr: 4 groups of 16 lanes -> 4 x 64B contiguous segments;
    // adjacent 64B halves of each 128B line merge in L2 (write-back).
    const int colb = w * 64 + m16;
#pragma unroll
    for (int ni = 0; ni < 4; ni++) {
#pragma unroll
        for (int reg = 0; reg < 4; reg++) {
            int rl = kg * 4 + reg;
            out[(size_t)rowid[rl] * OUT_STRIDE + colb + ni * 16] = acc[ni][reg];
        }
    }
}

extern "C" void kernel_launch(void* const* d_in, const int* in_sizes, int n_in,
                              void* d_out, int out_size, void* d_ws, size_t ws_size,
                              hipStream_t stream) {
    const float* x = (const float*)d_in[0];
    const float* w = (const float*)d_in[1];
    const int* wid = (const int*)d_in[2];
    float* out = (float*)d_out;

    unsigned short* wshuf = (unsigned short*)((char*)d_ws + WS_WSHUF);
    unsigned int* cnt = (unsigned int*)((char*)d_ws + WS_CNT);
    int* sorted = (int*)((char*)d_ws + WS_SORT);

    prep_kernel<<<256, 256, 0, stream>>>(w, wshuf, cnt);
    scatter_kernel<<<128, 256, 0, stream>>>(wid, cnt, sorted);
    gemm_kernel<<<2048, 512, 0, stream>>>(x, wshuf, cnt, sorted, out);
}